// Round 13
// baseline (103.801 us; speedup 1.0000x reference)
//
#include <hip/hip_runtime.h>
#include <hip/hip_bf16.h>

// B=64, T=128, D=512. gates = x @ w_ih^T per t; f-gate unused (c0=0).
// K1: per-(t, 64-col) block, 4 waves, reg-staged w (global->VGPR->cvt->LDS).
//     Substage = (cg, gate) over FULL K: each wave stages its 4 w-rows as
//     full 2KB contiguous reads (8 x dwordx4/lane) -> perfect DRAM page
//     sequentiality. 12 substages, 12 barriers, LDS dbuf 2x32KB,
//     DEPTH-2 prefetch (two rs sets) so each WRITE's loads were issued two
//     compute-phases (~1200+ cyc) earlier -> HBM latency covered.
//     x frags full-K resident (128 VGPR, loaded once). acc[3] per-cg +
//     per-cg epilogue. bf16x3 MFMA (hi*hi + hi*lo + lo*hi).
// K2: in-place softmax(20*h).

#define B_ 64
#define T_ 128
#define D_ 512

typedef float f32x4_t __attribute__((ext_vector_type(4)));
typedef __bf16 bf16x8_t __attribute__((ext_vector_type(8)));
typedef unsigned short u16x8_t __attribute__((ext_vector_type(8)));
typedef unsigned short u16x4_t __attribute__((ext_vector_type(4)));

#define SWZ(r) ((unsigned)(((r) & 7) << 4))

// Round-to-nearest split: f = hi + lo + O(2^-18 |f|).
__device__ __forceinline__ void cvt8(float4 a, float4 b, u16x8_t& hi, u16x8_t& lo) {
  float f[8] = {a.x, a.y, a.z, a.w, b.x, b.y, b.z, b.w};
#pragma unroll
  for (int j = 0; j < 8; ++j) {
    __bf16 h = (__bf16)f[j];
    hi[j] = __builtin_bit_cast(unsigned short, h);
    float r = f[j] - (float)h;
    lo[j] = __builtin_bit_cast(unsigned short, (__bf16)r);
  }
}

__device__ __forceinline__ void cvt4(float4 v, u16x4_t& hi, u16x4_t& lo) {
  float f[4] = {v.x, v.y, v.z, v.w};
#pragma unroll
  for (int j = 0; j < 4; ++j) {
    __bf16 h = (__bf16)f[j];
    hi[j] = __builtin_bit_cast(unsigned short, h);
    float r = f[j] - (float)h;
    lo[j] = __builtin_bit_cast(unsigned short, (__bf16)r);
  }
}

__device__ __forceinline__ f32x4_t mfma16(u16x8_t a, u16x8_t b, f32x4_t c) {
  return __builtin_amdgcn_mfma_f32_16x16x32_bf16(
      __builtin_bit_cast(bf16x8_t, a), __builtin_bit_cast(bf16x8_t, b), c, 0, 0, 0);
}

__device__ __forceinline__ float sigmoid_f(float v) { return 1.0f / (1.0f + __expf(-v)); }
__device__ __forceinline__ float tanh_f(float v) { return 1.0f - 2.0f / (__expf(2.0f * v) + 1.0f); }

// Grid 1024 = 128 t x 8 d-tiles. Wave wv stages w-rows wv*4..+4, computes b-rows wv*16..+16.
__global__ __launch_bounds__(256, 2) void lstm_gates_kernel(
    const float* __restrict__ x, const float* __restrict__ w, float* __restrict__ out) {
  __shared__ char lds[2][32768];  // 16 rows x 2KB (16 steps x [hi 64B | lo 64B])
  const int lane = threadIdx.x & 63;
  const int wv = threadIdx.x >> 6;
  const int bid = blockIdx.x;
  // XCD swizzle: 8 d-tiles of one t share an XCD -> x[t] L2-resident.
  const int work = (bid & 7) * 128 + (bid >> 3);
  const int t = work >> 3;
  const int d0 = (work & 7) << 6;

  const int c = lane & 15;   // frag row/col index
  const int kg = lane >> 4;  // k-subgroup 0..3

  // ---- x A-frags, full K, resident (128 VGPR). b-row wv*16+c, k = st*32+kg*8+j.
  const float* xrow = x + (((size_t)(wv * 16 + c) * T_ + t) << 9) + kg * 8;
  u16x8_t xh[16], xl[16];
#pragma unroll
  for (int st = 0; st < 16; ++st) {
    float4 a = *(const float4*)(xrow + st * 32);
    float4 b = *(const float4*)(xrow + st * 32 + 4);
    cvt8(a, b, xh[st], xl[st]);
  }

  // ---- LDS write addrs. Load i (0..7): row rl = wv*4 + (i>>1), K-half q = i&1;
  // lane holds floats f0 = q*256 + lane*4 -> step st_w = q*8 + (lane>>3),
  // low-byte (within 128B step blk) = (lane&7)*8, phys ^= SWZ(rl).
  unsigned wa_hi[8];
#pragma unroll
  for (int i = 0; i < 8; ++i) {
    const int rl = wv * 4 + (i >> 1);
    const unsigned stw = (unsigned)((i & 1) * 8 + (lane >> 3));
    wa_hi[i] = (unsigned)(rl * 2048) + stw * 128 +
               (((unsigned)((lane & 7) * 8)) ^ SWZ(rl));
  }
  // Read side: col c, step st, group kg; lo = hi ^ 64 (bit 6 = part).
  const unsigned q_hi = ((unsigned)(kg * 16)) ^ SWZ(c);
  const unsigned rbase = (unsigned)(c * 2048);

  const int grow[3] = {0, 1024, 1536};  // gate row bases i, g(2D), o(3D); f skipped
  const char* wt = (const char*)w + ((size_t)t << 22) + (size_t)d0 * 2048;

  f32x4_t acc[3];
#pragma unroll
  for (int g = 0; g < 3; ++g) acc[g] = (f32x4_t){0.f, 0.f, 0.f, 0.f};

  float4 rs0[8], rs1[8];  // two staging sets: 4 rows x 2KB each (8 x 16B/lane)

  // substage SS = cg*3 + g: rows grow[g] + cg*16 + wv*4 .. +4, full K.
#define WOFF(SS) ((size_t)(grow[(SS) % 3] + ((SS) / 3) * 16 + wv * 4) * 2048)

#define ISSUE(SS, RS)                                                           \
  do {                                                                          \
    const char* gb_ = wt + WOFF(SS) + lane * 16;                                \
    _Pragma("unroll") for (int i_ = 0; i_ < 8; ++i_)                            \
        RS[i_] = *(const float4*)(gb_ + (i_ >> 1) * 2048 + (i_ & 1) * 1024);    \
  } while (0)

#define WRITE(SS, RS)                                                           \
  do {                                                                          \
    char* lb_ = &lds[(SS) & 1][0];                                              \
    _Pragma("unroll") for (int i_ = 0; i_ < 8; ++i_) {                          \
      u16x4_t h_, l_;                                                           \
      cvt4(RS[i_], h_, l_);                                                     \
      *(u16x4_t*)(lb_ + wa_hi[i_]) = h_;                                        \
      *(u16x4_t*)(lb_ + (wa_hi[i_] ^ 64u)) = l_;                                \
    }                                                                           \
  } while (0)

#define BARRIER asm volatile("s_waitcnt lgkmcnt(0)\n\ts_barrier" ::: "memory")

#define COMPUTE(SS)                                                             \
  do {                                                                          \
    const char* lb_ = &lds[(SS) & 1][0];                                        \
    _Pragma("unroll") for (int st_ = 0; st_ < 16; ++st_) {                      \
      u16x8_t wh_ = *(const u16x8_t*)(lb_ + rbase + st_ * 128 + q_hi);          \
      u16x8_t wl_ = *(const u16x8_t*)(lb_ + rbase + st_ * 128 + (q_hi ^ 64u));  \
      acc[(SS) % 3] = mfma16(xh[st_], wh_, acc[(SS) % 3]);                      \
      acc[(SS) % 3] = mfma16(xh[st_], wl_, acc[(SS) % 3]);                      \
      acc[(SS) % 3] = mfma16(xl[st_], wh_, acc[(SS) % 3]);                      \
    }                                                                           \
  } while (0)

  // STEP: write current (data-dep waits loads issued 2 substages ago),
  // re-issue this rs set 2 ahead, one barrier, VMEM-free compute.
#define STEP(SS, RS)                        \
  WRITE(SS, RS);                            \
  if ((SS) + 2 < 12) ISSUE((SS) + 2, RS);   \
  BARRIER;                                  \
  COMPUTE(SS)

  // Per-cg epilogue: LSTM activation, store 16 cols, reset acc.
#define EPILOG(CG)                                                              \
  do {                                                                          \
    _Pragma("unroll") for (int j_ = 0; j_ < 4; ++j_) {                          \
      float iv_ = acc[0][j_], gv_ = acc[1][j_], ov_ = acc[2][j_];               \
      float cc_ = sigmoid_f(iv_) * tanh_f(gv_);                                 \
      float h_ = sigmoid_f(ov_) * tanh_f(cc_);                                  \
      int b_ = wv * 16 + kg * 4 + j_;                                           \
      out[(((size_t)b_ * T_ + t) << 9) + d0 + (CG) * 16 + c] = h_;              \
    }                                                                           \
    _Pragma("unroll") for (int g_ = 0; g_ < 3; ++g_)                            \
        acc[g_] = (f32x4_t){0.f, 0.f, 0.f, 0.f};                                \
  } while (0)

  ISSUE(0, rs0);
  ISSUE(1, rs1);
  STEP(0, rs0);  STEP(1, rs1);  STEP(2, rs0);  EPILOG(0);
  STEP(3, rs1);  STEP(4, rs0);  STEP(5, rs1);  EPILOG(1);
  STEP(6, rs0);  STEP(7, rs1);  STEP(8, rs0);  EPILOG(2);
  STEP(9, rs1);  STEP(10, rs0); STEP(11, rs1); EPILOG(3);

#undef EPILOG
#undef STEP
#undef COMPUTE
#undef WRITE
#undef ISSUE
#undef WOFF
}

// One wave per (b,t) row of 512; in-place softmax(20*h).
__global__ __launch_bounds__(256) void softmax_kernel(float* __restrict__ io) {
  const int lane = threadIdx.x & 63;
  const int row = blockIdx.x * 4 + (threadIdx.x >> 6);
  float* p = io + ((size_t)row << 9);
  float4 v0 = *(const float4*)(p + lane * 4);
  float4 v1 = *(const float4*)(p + 256 + lane * 4);
  float l[8] = {20.f * v0.x, 20.f * v0.y, 20.f * v0.z, 20.f * v0.w,
                20.f * v1.x, 20.f * v1.y, 20.f * v1.z, 20.f * v1.w};
  float m = l[0];
#pragma unroll
  for (int j = 1; j < 8; ++j) m = fmaxf(m, l[j]);
#pragma unroll
  for (int o = 32; o > 0; o >>= 1) m = fmaxf(m, __shfl_xor(m, o, 64));
  float e[8], s = 0.f;
#pragma unroll
  for (int j = 0; j < 8; ++j) {
    e[j] = __expf(l[j] - m);
    s += e[j];
  }
#pragma unroll
  for (int o = 32; o > 0; o >>= 1) s += __shfl_xor(s, o, 64);
  float inv = 1.0f / s;
  float4 o0 = {e[0] * inv, e[1] * inv, e[2] * inv, e[3] * inv};
  float4 o1 = {e[4] * inv, e[5] * inv, e[6] * inv, e[7] * inv};
  *(float4*)(p + lane * 4) = o0;
  *(float4*)(p + 256 + lane * 4) = o1;
}

extern "C" void kernel_launch(void* const* d_in, const int* in_sizes, int n_in,
                              void* d_out, int out_size, void* d_ws, size_t ws_size,
                              hipStream_t stream) {
  const float* x = (const float*)d_in[0];
  const float* w = (const float*)d_in[1];
  float* out = (float*)d_out;
  lstm_gates_kernel<<<T_ * 8, 256, 0, stream>>>(x, w, out);
  softmax_kernel<<<(B_ * T_) / 4, 256, 0, stream>>>(out);
}